// Round 1
// baseline (2347.627 us; speedup 1.0000x reference)
//
#include <hip/hip_runtime.h>
#include <math.h>
#include <stdint.h>

#define NTAGS 512
#define SEQL  512
#define BATCH 64
#define START_TAG 510
#define STOP_TAG  511
#define NEG_INF  -10000.0f

#define NB   64                 // 64 blocks x 8 waves = 512 waves; wave w of block b owns dst row 8b+w
#define BT   512
#define ROWS 8
#define MAXREPS 8               // slot replicas to spread poll contention; block polls replica bid&(reps-1)

// ws layout (bytes)
#define WS_NUM_OFF  0           // float numerator accumulator
#define WS_SLOT_OFF 256         // uint32 slots [SEQL+1][reps][NTAGS] — write-once, bits==0 means "not ready"
                                // (valid payloads are w = p/q in [1-eps, 512] -> never bit pattern 0)

#define AGLD(p)   __hip_atomic_load((p),      __ATOMIC_RELAXED, __HIP_MEMORY_SCOPE_AGENT)
#define AGST(p,v) __hip_atomic_store((p),(v), __ATOMIC_RELAXED, __HIP_MEMORY_SCOPE_AGENT)

// p = sum_src w*E, q = max_src w*E over the wave's 512 src elems (8 per lane, stride 64).
// Two independent butterflies interleaved -> single 6-stage cross-lane latency.
__device__ __forceinline__ void rowreduce(const float wv[8], const float treg[8],
                                          float& sp, float& mq)
{
    float t[8];
    #pragma unroll
    for (int q = 0; q < 8; ++q) t[q] = wv[q] * treg[q];
    sp = ((t[0] + t[1]) + (t[2] + t[3])) + ((t[4] + t[5]) + (t[6] + t[7]));
    mq = fmaxf(fmaxf(fmaxf(t[0], t[1]), fmaxf(t[2], t[3])),
               fmaxf(fmaxf(t[4], t[5]), fmaxf(t[6], t[7])));
    #pragma unroll
    for (int off = 32; off; off >>= 1) {
        const float ms = __shfl_xor(mq, off);
        const float ss = __shfl_xor(sp, off);
        mq = fmaxf(mq, ms);
        sp += ss;
    }
}

__global__ __launch_bounds__(BT) void crf_fused(
    const float* __restrict__ inputs, const int* __restrict__ tags,
    const float* __restrict__ trans, void* __restrict__ ws,
    float* __restrict__ out, const int reps)
{
    const int tid   = threadIdx.x;
    const int bid   = blockIdx.x;
    const int lane  = tid & 63;
    const int wave  = tid >> 6;
    const int myrow = bid * ROWS + wave;
    const int rep   = bid & (reps - 1);

    float*    numacc = (float*)((char*)ws + WS_NUM_OFF);
    uint32_t* slots  = (uint32_t*)((char*)ws + WS_SLOT_OFF);

    // ---- my transition row in EXP space: treg[q] = exp(T[myrow][lane+64q] (+1e4 for START row)) ----
    // Row START is uniformly -1e4; p/q is invariant to uniform row scaling, so shift it to exp(0)=1,
    // exactly reproducing the reference's lse-max cancellation. Column STOP underflows to 0.0 (== ref).
    float treg[8];
    {
        const float* trow  = trans + (size_t)myrow * NTAGS;
        const float  shift = (myrow == START_TAG) ? -NEG_INF : 0.0f;
        #pragma unroll
        for (int q = 0; q < 8; ++q) treg[q] = __expf(trow[lane + 64 * q] + shift);
    }

    // ---- numerator: block b == batch b, thread t == position t (unchanged from prior kernel) ----
    float ns;
    {
        const int*   tg  = tags + bid * SEQL;
        const float* inb = inputs + (size_t)bid * SEQL * NTAGS;
        if (tid > 0) {
            const int cur = tg[tid], prev = tg[tid - 1];
            ns = trans[cur * NTAGS + prev] + inb[(size_t)(tid - 1) * NTAGS + cur];
        } else {
            ns = trans[tg[0] * NTAGS + START_TAG] + trans[STOP_TAG * NTAGS + tg[SEQL - 1]];
        }
    }
    #pragma unroll
    for (int off = 32; off; off >>= 1) ns += __shfl_xor(ns, off);
    if (lane == 0) atomicAdd(numacc, ns);
    __builtin_amdgcn_s_waitcnt(0);   // RMW retired at coherence point before any slot publish

    // ---- w_0 = exp(fv_0): 1 at START, 0 elsewhere (level 0 never published) ----
    float wv[8];
    #pragma unroll
    for (int q = 0; q < 8; ++q) wv[q] = ((lane + 64 * q) == START_TAG) ? 1.0f : 0.0f;

    const size_t lvl_stride = (size_t)reps * NTAGS;      // u32 units per level

    // ---- main chain: iteration s consumes w_s (in regs), publishes+polls w_{s+1}. No LDS, no barriers. ----
    for (int s = 0; s < SEQL; ++s) {
        float sp, mq;
        rowreduce(wv, treg, sp, mq);
        const float wn = __fdividef(sp, mq);             // w_{s+1}[myrow] in [1, 512]

        const size_t base = (size_t)(s + 1) * lvl_stride;

        // publish to all replicas: lanes 0..reps-1, one store each (value is lane-uniform)
        if (lane < reps)
            AGST(slots + base + (size_t)lane * NTAGS + myrow, __float_as_uint(wn));

        // poll MY 8 needed slots straight into registers (coalesced 256B/load, 8 in flight)
        const uint32_t* pl = slots + base + (size_t)rep * NTAGS + lane;
        uint32_t g[8];
        #pragma unroll
        for (int q = 0; q < 8; ++q) g[q] = AGLD(pl + 64 * q);
        for (;;) {
            bool miss = false;
            #pragma unroll
            for (int q = 0; q < 8; ++q)
                if (g[q] == 0u) { g[q] = AGLD(pl + 64 * q); miss = true; }
            if (!__any(miss)) break;
        }
        #pragma unroll
        for (int q = 0; q < 8; ++q) wv[q] = __uint_as_float(g[q]);
    }

    // ---- terminal: row STOP wave does one more reduce on w_512 with treg == exp(T[STOP][*]) ----
    if (myrow == STOP_TAG) {
        float sp, mq;
        rowreduce(wv, treg, sp, mq);
        if (lane == 0) {
            const float ld  = __logf(sp) - __logf(mq);   // log_denominator (batch-independent)
            const float num = AGLD(numacc);
            out[0] = num - (float)BATCH * ld;
        }
    }
}

extern "C" void kernel_launch(void* const* d_in, const int* in_sizes, int n_in,
                              void* d_out, int out_size, void* d_ws, size_t ws_size,
                              hipStream_t stream)
{
    const float* inputs = (const float*)d_in[0];   // (64, 512, 512) fp32
    const int*   tags   = (const int*)  d_in[1];   // (64, 512) int32
    const float* trans  = (const float*)d_in[2];   // (512, 512) fp32
    float* out = (float*)d_out;

    // pick the largest replica count (power of 2, <=8) that fits the workspace
    int reps = MAXREPS;
    auto need = [](int r) {
        return (size_t)WS_SLOT_OFF + (size_t)(SEQL + 1) * (size_t)r * NTAGS * sizeof(uint32_t);
    };
    while (reps > 1 && need(reps) > ws_size) reps >>= 1;

    // zero numerator accumulator + write-once slot ring (0 == "not yet published")
    hipMemsetAsync(d_ws, 0, need(reps), stream);

    crf_fused<<<NB, BT, 0, stream>>>(inputs, tags, trans, d_ws, out, reps);
}

// Round 2
// 1892.654 us; speedup vs baseline: 1.2404x; 1.2404x over previous
//
#include <hip/hip_runtime.h>
#include <math.h>
#include <stdint.h>

#define NTAGS 512
#define SEQL  512
#define BATCH 64
#define START_TAG 510
#define STOP_TAG  511
#define NEG_INF  -10000.0f

// 8 blocks x 16 waves = 128 waves; wave w of block b owns dst rows [b*64+w*4, b*64+w*4+4).
// Rationale: the chain is latency-bound through the agent-scope coherence point; shrinking
// publishers 4096->512 stores/step and pollers 32K->4K cuts LLC queueing + convoy jitter,
// while per-wave compute (4 rows, ~200 VALU ops) stays ~150ns — far off the critical path.
#define NB   8
#define BT   1024
#define RPB  64                 // rows per block
#define RPW  4                  // rows per wave
#define NW   16                 // waves per block
#define RING 8                  // slot ring depth (levels mod 8); skew across blocks is <=1 step,
                                // so a reused ring slot has >=7 steps of slack after consumer-zeroing

// ws layout (bytes)
#define WS_NUM_OFF  0           // float numerator accumulator
#define WS_SLOT_OFF 256         // u32 slots [RING][NB replicas][NTAGS]; bits==0 means "not ready"
                                // (payload w = sum/max in [1,512] -> never bit pattern 0)
#define WS_BYTES    (WS_SLOT_OFF + (size_t)RING * NB * NTAGS * 4)

#define AGLD(p)   __hip_atomic_load((p),      __ATOMIC_RELAXED, __HIP_MEMORY_SCOPE_AGENT)
#define AGST(p,v) __hip_atomic_store((p),(v), __ATOMIC_RELAXED, __HIP_MEMORY_SCOPE_AGENT)

__global__ __launch_bounds__(BT) void crf_fused(
    const float* __restrict__ inputs, const int* __restrict__ tags,
    const float* __restrict__ trans, void* __restrict__ ws,
    float* __restrict__ out)
{
    __shared__ float wlds[2][NTAGS];        // 4 KB ping-pong of w (one sync per step)

    const int tid   = threadIdx.x;
    const int bid   = blockIdx.x;
    const int lane  = tid & 63;
    const int wave  = tid >> 6;
    const int row0  = bid * RPB + wave * RPW;

    float*    numacc = (float*)((char*)ws + WS_NUM_OFF);
    uint32_t* slots  = (uint32_t*)((char*)ws + WS_SLOT_OFF);

    // ---- my 4 transition rows in EXP space: treg[i][q] = exp(T[row0+i][lane+64q]) ----
    // Row START is uniformly -1e4; p/q is invariant to uniform row scaling, so shift it to
    // exp(0)=1 (reproduces the reference's lse-max cancellation). Column STOP underflows to 0.
    float treg[RPW][8];
    #pragma unroll
    for (int i = 0; i < RPW; ++i) {
        const int   r     = row0 + i;
        const float shift = (r == START_TAG) ? -NEG_INF : 0.0f;
        const float* trow = trans + (size_t)r * NTAGS;
        #pragma unroll
        for (int q = 0; q < 8; ++q)
            treg[i][q] = __expf(trow[lane + 64 * q] + shift);   // coalesced 256B/wave
    }

    // ---- numerator: 16 teams of 512 threads cover 64 batches, 4 each ----
    {
        const int half = tid >> 9;              // 0/1: two 512-thread teams per block
        const int pos  = tid & 511;
        #pragma unroll
        for (int it = 0; it < 4; ++it) {
            const int    b   = bid * 8 + half + 2 * it;
            const int*   tg  = tags + b * SEQL;
            const float* inb = inputs + (size_t)b * SEQL * NTAGS;
            float ns;
            if (pos > 0) {
                const int cur = tg[pos], prev = tg[pos - 1];
                ns = trans[cur * NTAGS + prev] + inb[(size_t)(pos - 1) * NTAGS + cur];
            } else {
                ns = trans[tg[0] * NTAGS + START_TAG] + trans[STOP_TAG * NTAGS + tg[SEQL - 1]];
            }
            #pragma unroll
            for (int off = 32; off; off >>= 1) ns += __shfl_xor(ns, off);
            if (lane == 0) atomicAdd(numacc, ns);
        }
        __builtin_amdgcn_s_waitcnt(0);  // RMWs retired at coherence point before any slot publish
    }

    // ---- w_0 = exp(fv_0): one-hot at START (level 0 never published) ----
    if (tid < NTAGS) wlds[0][tid] = (tid == START_TAG) ? 1.0f : 0.0f;
    __syncthreads();

    // ---- main chain: step s consumes w_s (LDS), publishes + polls w_{s+1}. One barrier/step. ----
    for (int s = 0; s < SEQL; ++s) {
        const int cur  = s & 1, nxt = cur ^ 1;
        const int ring = (s + 1) & (RING - 1);
        uint32_t* lvl    = slots + (size_t)ring * NB * NTAGS;
        uint32_t* myslot = lvl + (size_t)bid * NTAGS + tid;      // valid for tid<512

        // early probe: overlaps compute+publish (others' s+1 may already have arrived)
        uint32_t p = (tid < NTAGS) ? AGLD(myslot) : 1u;

        // ---- 4 rows: t = w.*E[row]; sp = sum, mq = max; 8 butterflies interleaved ----
        float wv[8];
        #pragma unroll
        for (int q = 0; q < 8; ++q) wv[q] = wlds[cur][lane + 64 * q];  // 2-way alias only (free)

        float sp[RPW], mq[RPW];
        #pragma unroll
        for (int i = 0; i < RPW; ++i) {
            const float t0 = wv[0] * treg[i][0], t1 = wv[1] * treg[i][1],
                        t2 = wv[2] * treg[i][2], t3 = wv[3] * treg[i][3],
                        t4 = wv[4] * treg[i][4], t5 = wv[5] * treg[i][5],
                        t6 = wv[6] * treg[i][6], t7 = wv[7] * treg[i][7];
            sp[i] = ((t0 + t1) + (t2 + t3)) + ((t4 + t5) + (t6 + t7));
            mq[i] = fmaxf(fmaxf(fmaxf(t0, t1), fmaxf(t2, t3)),
                          fmaxf(fmaxf(t4, t5), fmaxf(t6, t7)));
        }
        #pragma unroll
        for (int off = 32; off; off >>= 1) {
            #pragma unroll
            for (int i = 0; i < RPW; ++i) {
                const float a = __shfl_xor(sp[i], off);
                const float b = __shfl_xor(mq[i], off);
                sp[i] += a; mq[i] = fmaxf(mq[i], b);
            }
        }

        // ---- publish: lanes 0..31 -> 4 rows x 8 replicas, one store each ----
        if (lane < 32) {
            const int   i  = lane >> 3, rp = lane & 7;
            const float wn = __fdividef(sp[i], mq[i]);           // w in [1,512]: bits never 0
            AGST(lvl + (size_t)rp * NTAGS + (row0 + i), __float_as_uint(wn));
        }

        // ---- per-thread single-slot poll (4 loads in flight), then LDS rebroadcast ----
        if (tid < NTAGS) {
            if (p == 0u) {
                uint32_t q0 = AGLD(myslot), q1 = AGLD(myslot),
                         q2 = AGLD(myslot), q3 = AGLD(myslot);
                for (;;) {
                    if (q0) { p = q0; break; }
                    q0 = AGLD(myslot);
                    if (q1) { p = q1; break; }
                    q1 = AGLD(myslot);
                    if (q2) { p = q2; break; }
                    q2 = AGLD(myslot);
                    if (q3) { p = q3; break; }
                    q3 = AGLD(myslot);
                }
            }
            AGST(myslot, 0u);                   // recycle ring slot (>=7 steps of slack)
            wlds[nxt][tid] = __uint_as_float(p);
        }
        __syncthreads();
    }

    // ---- terminal: wave owning row STOP (block 7, wave 15, i=3); w_512 is in wlds[0] ----
    if (bid == NB - 1 && wave == NW - 1) {
        float wv[8];
        #pragma unroll
        for (int q = 0; q < 8; ++q) wv[q] = wlds[0][lane + 64 * q];
        const float t0 = wv[0] * treg[3][0], t1 = wv[1] * treg[3][1],
                    t2 = wv[2] * treg[3][2], t3 = wv[3] * treg[3][3],
                    t4 = wv[4] * treg[3][4], t5 = wv[5] * treg[3][5],
                    t6 = wv[6] * treg[3][6], t7 = wv[7] * treg[3][7];
        float sp = ((t0 + t1) + (t2 + t3)) + ((t4 + t5) + (t6 + t7));
        float mq = fmaxf(fmaxf(fmaxf(t0, t1), fmaxf(t2, t3)),
                         fmaxf(fmaxf(t4, t5), fmaxf(t6, t7)));
        #pragma unroll
        for (int off = 32; off; off >>= 1) {
            const float a = __shfl_xor(sp, off);
            const float b = __shfl_xor(mq, off);
            sp += a; mq = fmaxf(mq, b);
        }
        if (lane == 0) {
            const float ld  = __logf(sp) - __logf(mq);           // log_denominator
            const float num = AGLD(numacc);
            out[0] = num - (float)BATCH * ld;
        }
    }
}

extern "C" void kernel_launch(void* const* d_in, const int* in_sizes, int n_in,
                              void* d_out, int out_size, void* d_ws, size_t ws_size,
                              hipStream_t stream)
{
    const float* inputs = (const float*)d_in[0];   // (64, 512, 512) fp32
    const int*   tags   = (const int*)  d_in[1];   // (64, 512) int32
    const float* trans  = (const float*)d_in[2];   // (512, 512) fp32
    float* out = (float*)d_out;

    // zero numerator accumulator + 128KB ring (0 == "not yet published")
    hipMemsetAsync(d_ws, 0, WS_BYTES, stream);

    crf_fused<<<NB, BT, 0, stream>>>(inputs, tags, trans, d_ws, out);
}

// Round 3
// 893.063 us; speedup vs baseline: 2.6287x; 2.1193x over previous
//
#include <hip/hip_runtime.h>
#include <math.h>
#include <stdint.h>

#define NTAGS 512
#define SEQL  512
#define BATCH 64
#define START_TAG 510
#define STOP_TAG  511
#define NEG_INF  -10000.0f

#define NB   64                 // R0's proven shape: block b owns rows [8b,8b+8); 1 row/wave
#define BT   512
#define ROWS 8
#define REPS 8                  // slot replicas; block polls replica bid&7

// ws layout (bytes)
#define WS_NUM_OFF  0                     // float numerator accumulator
#define WS_SLOT_OFF 256                   // uint64 slots [2][REPS][NTAGS]: (step<<32)|f32bits
#define WS_BYTES    (WS_SLOT_OFF + 2 * REPS * NTAGS * 8)

#define AGLD(p)   __hip_atomic_load((p),      __ATOMIC_RELAXED, __HIP_MEMORY_SCOPE_AGENT)
#define AGST(p,v) __hip_atomic_store((p),(v), __ATOMIC_RELAXED, __HIP_MEMORY_SCOPE_AGENT)

__global__ __launch_bounds__(BT) void crf_fused(
    const float* __restrict__ inputs, const int* __restrict__ tags,
    const float* __restrict__ trans, void* __restrict__ ws,
    float* __restrict__ out)
{
    __shared__ float wlds[2][NTAGS];        // 4 KB ping-pong of w = exp(fv) (renormalized)
    __shared__ int   conv[2][2][ROWS];      // [phase s&1][eq1/eq2][wave] — double-buffered: no
                                            // read/write race across the single per-step barrier

    const int tid   = threadIdx.x;
    const int bid   = blockIdx.x;
    const int lane  = tid & 63;
    const int wave  = tid >> 6;
    const int myrow = bid * ROWS + wave;
    const int rep   = bid & (REPS - 1);

    float*    numacc = (float*)((char*)ws + WS_NUM_OFF);
    uint64_t* slots  = (uint64_t*)((char*)ws + WS_SLOT_OFF);

    // ---- my transition row in EXP space: treg[q] = exp(T[myrow][lane+64q]) ----
    // Row START is uniformly -1e4; w'=p/q is invariant to uniform row scaling, so shift it
    // to exp(0)=1 (reproduces the reference's lse-max cancellation; validated absmax=0 R1/R2).
    float treg[8];
    {
        const float* trow  = trans + (size_t)myrow * NTAGS;
        const float  shift = (myrow == START_TAG) ? -NEG_INF : 0.0f;
        #pragma unroll
        for (int q = 0; q < 8; ++q)
            treg[q] = __expf(trow[lane + 64 * q] + shift);       // coalesced 256B/wave
    }

    // ---- numerator: block b == batch b, thread t == position t (R0 verbatim) ----
    float ns;
    {
        const int*   tg  = tags + bid * SEQL;
        const float* inb = inputs + (size_t)bid * SEQL * NTAGS;
        if (tid > 0) {
            const int cur = tg[tid], prev = tg[tid - 1];
            ns = trans[cur * NTAGS + prev] + inb[(size_t)(tid - 1) * NTAGS + cur];
        } else {
            ns = trans[tg[0] * NTAGS + START_TAG] + trans[STOP_TAG * NTAGS + tg[SEQL - 1]];
        }
    }
    #pragma unroll
    for (int off = 32; off; off >>= 1) ns += __shfl_xor(ns, off);
    if (lane == 0) atomicAdd(numacc, ns);
    __builtin_amdgcn_s_waitcnt(0);   // RMW retired at coherence point before any slot publish

    // ---- w_0: one-hot at START (level 0 never published). wlds[1]=0 so s=0 eq2 is false. ----
    wlds[0][tid] = (tid == START_TAG) ? 1.0f : 0.0f;
    wlds[1][tid] = 0.0f;
    __syncthreads();

    int sel = 0;    // ping-pong buffer holding fv_512 at exit (0 for full run and period-2; see below)

    for (int s = 0; s < SEQL; ++s) {
        const int ph = s & 1, nxt = ph ^ 1;                      // wlds[ph]=w_s, wlds[nxt]=w_{s-1}
        uint64_t* pubbase = slots + (size_t)nxt * REPS * NTAGS;
        uint64_t* myslot  = slots + ((size_t)nxt * REPS + rep) * NTAGS + tid;
        const unsigned want = (unsigned)(s + 1);

        // early probe: overlaps compute + publish (others' s+1 may already have arrived)
        uint64_t p = AGLD(myslot);

        // ---- my row: t = w .* E[row]; sp = sum, mq = max; two interleaved butterflies ----
        float t[8];
        #pragma unroll
        for (int q = 0; q < 8; ++q)
            t[q] = wlds[ph][lane + 64 * q] * treg[q];            // 2-way LDS alias only (free)

        float sp = ((t[0] + t[1]) + (t[2] + t[3])) + ((t[4] + t[5]) + (t[6] + t[7]));
        float mq = fmaxf(fmaxf(fmaxf(t[0], t[1]), fmaxf(t[2], t[3])),
                         fmaxf(fmaxf(t[4], t[5]), fmaxf(t[6], t[7])));
        #pragma unroll
        for (int off = 32; off; off >>= 1) {
            const float a = __shfl_xor(sp, off);
            const float b = __shfl_xor(mq, off);
            sp += a; mq = fmaxf(mq, b);
        }

        // publish w' = sp/mq in [1,512]; lanes 0-7 cover all 8 replicas in one instruction
        {
            const float    wn = __fdividef(sp, mq);
            const uint64_t pk = ((uint64_t)want << 32) | (uint64_t)__float_as_uint(wn);
            if (lane < REPS)
                AGST(pubbase + (size_t)lane * NTAGS + myrow, pk);
        }

        // ---- pipelined poll of MY single slot (replica bid&7): 4 loads in flight (R0 verbatim) ----
        if ((unsigned)(p >> 32) != want) {
            uint64_t q0 = AGLD(myslot), q1 = AGLD(myslot),
                     q2 = AGLD(myslot), q3 = AGLD(myslot);
            for (;;) {
                if ((unsigned)(q0 >> 32) == want) { p = q0; break; }
                q0 = AGLD(myslot);
                if ((unsigned)(q1 >> 32) == want) { p = q1; break; }
                q1 = AGLD(myslot);
                if ((unsigned)(q2 >> 32) == want) { p = q2; break; }
                q2 = AGLD(myslot);
                if ((unsigned)(q3 >> 32) == want) { p = q3; break; }
                q3 = AGLD(myslot);
            }
        }

        // ---- bitwise-cycle detection (exact): eq1 vs w_s, eq2 vs w_{s-1}; then rebroadcast ----
        const unsigned nv  = (unsigned)(p & 0xFFFFFFFFu);
        const int eq1 = (nv == __float_as_uint(wlds[ph][tid]));
        const int eq2 = (nv == __float_as_uint(wlds[nxt][tid]));
        wlds[nxt][tid] = __uint_as_float(nv);
        const int e1 = __all(eq1), e2 = __all(eq2);
        if (lane == 0) { conv[ph][0][wave] = e1; conv[ph][1][wave] = e2; }
        __syncthreads();   // depth-2 ping-pong: one sync per step suffices (R0 verbatim)

        // Uniform decision on bit-identical data -> all waves of ALL blocks break together.
        int c1 = conv[ph][0][0], c2 = conv[ph][1][0];
        #pragma unroll
        for (int w2 = 1; w2 < ROWS; ++w2) { c1 &= conv[ph][0][w2]; c2 &= conv[ph][1][w2]; }
        if (c1) { sel = nxt; break; }   // fixed point: w_512 == w_{s+1} bitwise
        if (c2) { sel = 0;   break; }   // period-2: remaining = 511-s; parity puts w_512 in buf 0
                                        // (s even -> w_s in buf 0; s odd -> w_{s+1} in buf 0)
    }

    // ---- terminal by the wave that owns row STOP (block 63, wave 7); treg == exp(T[STOP][*]) ----
    if (myrow == STOP_TAG) {
        float t[8];
        #pragma unroll
        for (int q = 0; q < 8; ++q)
            t[q] = wlds[sel][lane + 64 * q] * treg[q];
        float sp = ((t[0] + t[1]) + (t[2] + t[3])) + ((t[4] + t[5]) + (t[6] + t[7]));
        float mq = fmaxf(fmaxf(fmaxf(t[0], t[1]), fmaxf(t[2], t[3])),
                         fmaxf(fmaxf(t[4], t[5]), fmaxf(t[6], t[7])));
        #pragma unroll
        for (int off = 32; off; off >>= 1) {
            const float a = __shfl_xor(sp, off);
            const float b = __shfl_xor(mq, off);
            sp += a; mq = fmaxf(mq, b);
        }
        if (lane == 0) {
            const float ld  = __logf(sp) - __logf(mq);           // log_denominator (batch-invariant)
            const float num = AGLD(numacc);
            out[0] = num - (float)BATCH * ld;
        }
    }
}

extern "C" void kernel_launch(void* const* d_in, const int* in_sizes, int n_in,
                              void* d_out, int out_size, void* d_ws, size_t ws_size,
                              hipStream_t stream)
{
    const float* inputs = (const float*)d_in[0];   // (64, 512, 512) fp32
    const int*   tags   = (const int*)  d_in[1];   // (64, 512) int32
    const float* trans  = (const float*)d_in[2];   // (512, 512) fp32
    float* out = (float*)d_out;

    // zero numerator accumulator + tagged slot buffers (valid tags are 1..512)
    hipMemsetAsync(d_ws, 0, WS_BYTES, stream);

    crf_fused<<<NB, BT, 0, stream>>>(inputs, tags, trans, d_ws, out);
}

// Round 4
// 841.627 us; speedup vs baseline: 2.7894x; 1.0611x over previous
//
#include <hip/hip_runtime.h>
#include <math.h>
#include <stdint.h>

#define NTAGS 512
#define SEQL  512
#define BATCH 64
#define START_TAG 510
#define STOP_TAG  511
#define NEG_INF  -10000.0f

#define NB   64                 // block b owns rows [8b,8b+8); 1 row/wave (R0's proven shape)
#define BT   512
#define ROWS 8
#define REPS 8                  // slot replicas; block polls replica bid&7

// Early-exit: the recursion fv'=lse(fv+T)-max(fv+T) is emission-independent, i.e. a FIXED
// positive-matrix map iterated 512x. It contracts (est. |l2/l1|~0.12), so consecutive
// iterates agree to ~1e-7 relative by step ~12 and stay there (R3 showed bitwise equality
// never happens -- rounding noise ball). Exiting at relative tol EPS leaves w within
// ~EPS*k/(1-k) of w_512 => output error ~64*3e-7 ~ 2e-5. Uniform across blocks (identical
// bits everywhere), exit after publish => no stranded pollers. No exit => full 512 steps.
#define EPS 1e-6f

// ws layout (bytes)
#define WS_NUM_OFF  0                     // float numerator accumulator
#define WS_SLOT_OFF 256                   // uint64 slots [2][REPS][NTAGS]: (step<<32)|f32bits
#define WS_BYTES    (WS_SLOT_OFF + 2 * REPS * NTAGS * 8)

#define AGLD(p)   __hip_atomic_load((p),      __ATOMIC_RELAXED, __HIP_MEMORY_SCOPE_AGENT)
#define AGST(p,v) __hip_atomic_store((p),(v), __ATOMIC_RELAXED, __HIP_MEMORY_SCOPE_AGENT)

__global__ __launch_bounds__(BT) void crf_fused(
    const float* __restrict__ inputs, const int* __restrict__ tags,
    const float* __restrict__ trans, void* __restrict__ ws,
    float* __restrict__ out)
{
    __shared__ float wlds[2][NTAGS];        // 4 KB ping-pong of w = exp(fv) (renormalized)
    __shared__ int   conv[2][ROWS];         // [phase s&1][wave] — double-buffered across the
                                            // single per-step barrier (no read/write race)

    const int tid   = threadIdx.x;
    const int bid   = blockIdx.x;
    const int lane  = tid & 63;
    const int wave  = tid >> 6;
    const int myrow = bid * ROWS + wave;
    const int rep   = bid & (REPS - 1);

    float*    numacc = (float*)((char*)ws + WS_NUM_OFF);
    uint64_t* slots  = (uint64_t*)((char*)ws + WS_SLOT_OFF);

    // ---- my transition row in EXP space: treg[q] = exp(T[myrow][lane+64q]) ----
    // Row START is uniformly -1e4; w'=p/q is invariant to uniform row scaling, so shift it
    // to exp(0)=1 (reproduces the reference's lse-max cancellation; validated absmax=0 R1-R3).
    float treg[8];
    {
        const float* trow  = trans + (size_t)myrow * NTAGS;
        const float  shift = (myrow == START_TAG) ? -NEG_INF : 0.0f;
        #pragma unroll
        for (int q = 0; q < 8; ++q)
            treg[q] = __expf(trow[lane + 64 * q] + shift);       // coalesced 256B/wave
    }

    // ---- numerator: block b == batch b, thread t == position t (R0 verbatim) ----
    float ns;
    {
        const int*   tg  = tags + bid * SEQL;
        const float* inb = inputs + (size_t)bid * SEQL * NTAGS;
        if (tid > 0) {
            const int cur = tg[tid], prev = tg[tid - 1];
            ns = trans[cur * NTAGS + prev] + inb[(size_t)(tid - 1) * NTAGS + cur];
        } else {
            ns = trans[tg[0] * NTAGS + START_TAG] + trans[STOP_TAG * NTAGS + tg[SEQL - 1]];
        }
    }
    #pragma unroll
    for (int off = 32; off; off >>= 1) ns += __shfl_xor(ns, off);
    if (lane == 0) atomicAdd(numacc, ns);
    __builtin_amdgcn_s_waitcnt(0);   // RMW retired at coherence point before any slot publish

    // ---- w_0: one-hot at START (level 0 never published) ----
    wlds[0][tid] = (tid == START_TAG) ? 1.0f : 0.0f;
    wlds[1][tid] = 0.0f;
    __syncthreads();

    int sel = 0;    // buffer holding the final w at exit (full run: w_512, 512 even -> buffer 0)

    for (int s = 0; s < SEQL; ++s) {
        const int ph = s & 1, nxt = ph ^ 1;                      // wlds[ph] = w_s
        uint64_t* pubbase = slots + (size_t)nxt * REPS * NTAGS;
        uint64_t* myslot  = slots + ((size_t)nxt * REPS + rep) * NTAGS + tid;
        const unsigned want = (unsigned)(s + 1);

        // early probe: overlaps compute + publish (others' s+1 may already have arrived)
        uint64_t p = AGLD(myslot);

        // ---- my row: t = w .* E[row]; sp = sum, mq = max; two interleaved butterflies ----
        float t[8];
        #pragma unroll
        for (int q = 0; q < 8; ++q)
            t[q] = wlds[ph][lane + 64 * q] * treg[q];            // 2-way LDS alias only (free)

        float sp = ((t[0] + t[1]) + (t[2] + t[3])) + ((t[4] + t[5]) + (t[6] + t[7]));
        float mq = fmaxf(fmaxf(fmaxf(t[0], t[1]), fmaxf(t[2], t[3])),
                         fmaxf(fmaxf(t[4], t[5]), fmaxf(t[6], t[7])));
        #pragma unroll
        for (int off = 32; off; off >>= 1) {
            const float a = __shfl_xor(sp, off);
            const float b = __shfl_xor(mq, off);
            sp += a; mq = fmaxf(mq, b);
        }

        // publish w' = sp/mq in [1,512]; lanes 0-7 cover all 8 replicas in one instruction
        {
            const float    wn = __fdividef(sp, mq);
            const uint64_t pk = ((uint64_t)want << 32) | (uint64_t)__float_as_uint(wn);
            if (lane < REPS)
                AGST(pubbase + (size_t)lane * NTAGS + myrow, pk);
        }

        // ---- pipelined poll of MY single slot (replica bid&7): 4 loads in flight ----
        if ((unsigned)(p >> 32) != want) {
            uint64_t q0 = AGLD(myslot), q1 = AGLD(myslot),
                     q2 = AGLD(myslot), q3 = AGLD(myslot);
            for (;;) {
                if ((unsigned)(q0 >> 32) == want) { p = q0; break; }
                q0 = AGLD(myslot);
                if ((unsigned)(q1 >> 32) == want) { p = q1; break; }
                q1 = AGLD(myslot);
                if ((unsigned)(q2 >> 32) == want) { p = q2; break; }
                q2 = AGLD(myslot);
                if ((unsigned)(q3 >> 32) == want) { p = q3; break; }
                q3 = AGLD(myslot);
            }
        }

        // ---- approximate fixed-point test: |w_{s+1} - w_s| <= EPS * w_s, all 512 comps ----
        const float nvf = __uint_as_float((unsigned)(p & 0xFFFFFFFFu));
        const float old = wlds[ph][tid];
        const int   eq  = (fabsf(nvf - old) <= EPS * old);       // w >= 1: no div-by-zero
        wlds[nxt][tid] = nvf;
        const int e1 = __all(eq);
        if (lane == 0) conv[ph][wave] = e1;
        __syncthreads();   // depth-2 ping-pong: one sync per step suffices

        // Uniform decision on bit-identical data -> all waves of ALL blocks break together.
        int c1 = conv[ph][0];
        #pragma unroll
        for (int w2 = 1; w2 < ROWS; ++w2) c1 &= conv[ph][w2];
        if (c1) { sel = nxt; break; }    // w_{s+1} ~ w* ~ w_512 within ~EPS*k/(1-k)
    }

    // ---- terminal by the wave that owns row STOP (block 63, wave 7); treg == exp(T[STOP][*]) ----
    if (myrow == STOP_TAG) {
        float t[8];
        #pragma unroll
        for (int q = 0; q < 8; ++q)
            t[q] = wlds[sel][lane + 64 * q] * treg[q];
        float sp = ((t[0] + t[1]) + (t[2] + t[3])) + ((t[4] + t[5]) + (t[6] + t[7]));
        float mq = fmaxf(fmaxf(fmaxf(t[0], t[1]), fmaxf(t[2], t[3])),
                         fmaxf(fmaxf(t[4], t[5]), fmaxf(t[6], t[7])));
        #pragma unroll
        for (int off = 32; off; off >>= 1) {
            const float a = __shfl_xor(sp, off);
            const float b = __shfl_xor(mq, off);
            sp += a; mq = fmaxf(mq, b);
        }
        if (lane == 0) {
            const float ld  = __logf(sp) - __logf(mq);           // log_denominator (batch-invariant)
            const float num = AGLD(numacc);
            out[0] = num - (float)BATCH * ld;
        }
    }
}

extern "C" void kernel_launch(void* const* d_in, const int* in_sizes, int n_in,
                              void* d_out, int out_size, void* d_ws, size_t ws_size,
                              hipStream_t stream)
{
    const float* inputs = (const float*)d_in[0];   // (64, 512, 512) fp32
    const int*   tags   = (const int*)  d_in[1];   // (64, 512) int32
    const float* trans  = (const float*)d_in[2];   // (512, 512) fp32
    float* out = (float*)d_out;

    // zero numerator accumulator + tagged slot buffers (valid tags are 1..512)
    hipMemsetAsync(d_ws, 0, WS_BYTES, stream);

    crf_fused<<<NB, BT, 0, stream>>>(inputs, tags, trans, d_ws, out);
}